// Round 2
// baseline (1285.127 us; speedup 1.0000x reference)
//
#include <hip/hip_runtime.h>

// Batched thin QR (Householder, LAPACK sign convention) for 8192 x (256x16) fp32.
// One 64-lane wave per matrix; lane l owns rows {l, l+64, l+128, l+192} in registers.
//
// Round-2 structure (compact-WY):
//   Phase 1: upfront column norms (16 independent butterfly reductions), downdated
//            each iteration -> only ONE serial reduction batch per factorization step.
//   Phase 2: Householder factorization; at step j dot u_j against ALL other columns
//            (t>j -> w for the trailing update, t<j -> Gram g_ij for WY). u_j overwrites
//            column j in place. Uniform scalars (g, U1 rows) persist in 5 distributed
//            VGPRs (lane-indexed, compile-time readlane).
//   Phase 3: Z = U*T in place via z_j = u_j - sum_{i<j} z_i g_ij  (pure VALU, no ds).
//   Phase 4: Q = E - Z*U1^T in place, right-to-left           (pure VALU, no ds).

constexpr int BATCH = 8192;
constexpr int DROWS = 256;
constexpr int QC    = 16;

__global__ __launch_bounds__(256) void qr_wy_kernel(
    const float* __restrict__ in, float* __restrict__ out)
{
    const int lane = threadIdx.x & 63;
    const int wid  = threadIdx.x >> 6;
    const int b    = blockIdx.x * 4 + wid;

    const float4* __restrict__ A4 = (const float4*)(in  + (size_t)b * (DROWS * QC));
    float4*       __restrict__ O4 = (float4*)      (out + (size_t)b * (DROWS * QC));

    float x[4][QC];   // columns; progressively overwritten by u_j, then z_j, then Q

    // ---- load ----
#pragma unroll
    for (int s = 0; s < 4; ++s) {
        const int rr = s * 64 + lane;
#pragma unroll
        for (int q4 = 0; q4 < 4; ++q4) {
            float4 t = A4[rr * 4 + q4];
            x[s][q4*4+0] = t.x; x[s][q4*4+1] = t.y;
            x[s][q4*4+2] = t.z; x[s][q4*4+3] = t.w;
        }
    }

    // ---- upfront column norms^2 (independent reductions, pipelined) ----
    float nrm2[QC];
#pragma unroll
    for (int k = 0; k < QC; ++k) {
        float p = x[0][k]*x[0][k] + x[1][k]*x[1][k] + x[2][k]*x[2][k] + x[3][k]*x[3][k];
#pragma unroll
        for (int m = 1; m < 64; m <<= 1) p += __shfl_xor(p, m, 64);
        nrm2[k] = p;   // uniform across lanes; downdated to "rows >= j" as rows freeze
    }

    // distributed uniform-scalar storage (value for index p lives at lane p%64):
    float gd0 = 0.f, gd1 = 0.f;            // Gram g_ij = u_i.u_j, pair p = j(j-1)/2 + i  (p<120)
    float ud0 = 0.f, ud1 = 0.f, ud2 = 0.f; // U1[k][j] = u_j[row k], j<=k, q = k(k+1)/2 + j (q<136)

    // ---- Householder factorization ----
#pragma unroll
    for (int j = 0; j < QC; ++j) {
        const float xjj   = __shfl(x[0][j], j, 64);          // pivot (row j)
        const float nrm   = sqrtf(nrm2[j]);
        const float alpha = -copysignf(nrm, xjj);            // LAPACK dlarfg sign
        const float vtv   = 2.f * (nrm2[j] - alpha * xjj);   // no cancellation (sign choice)
        const float sc    = sqrtf(2.f / vtv);                // u = v*sc => H = I - u u'

        // form u_j in place (rows < j zeroed; only slot 0 can hold rows < 16)
        x[0][j] = ((lane < j) ? 0.f : (lane == j ? (xjj - alpha) : x[0][j])) * sc;
        x[1][j] *= sc; x[2][j] *= sc; x[3][j] *= sc;

        // persist U1 entries of u_j (rows j..15 live in slot 0, lanes j..15)
#pragma unroll
        for (int k = j; k < QC; ++k) {
            const float v = __shfl(x[0][j], k, 64);          // compile-time lane -> readlane
            const int q = k*(k+1)/2 + j;
            if (q < 64)       ud0 = (lane ==  q       ) ? v : ud0;
            else if (q < 128) ud1 = (lane == (q - 64 )) ? v : ud1;
            else              ud2 = (lane == (q - 128)) ? v : ud2;
        }

        // dot u_j against every other column: t<j -> Gram, t>j -> w (all independent)
        float w[QC];
#pragma unroll
        for (int t = 0; t < QC; ++t) {
            if (t == j) continue;
            float d = x[0][j]*x[0][t] + x[1][j]*x[1][t] + x[2][j]*x[2][t] + x[3][j]*x[3][t];
#pragma unroll
            for (int m = 1; m < 64; m <<= 1) d += __shfl_xor(d, m, 64);
            w[t] = d;
        }

        // persist Gram column
#pragma unroll
        for (int i = 0; i < j; ++i) {
            const int p = j*(j-1)/2 + i;
            if (p < 64) gd0 = (lane ==  p      ) ? w[i] : gd0;
            else        gd1 = (lane == (p - 64)) ? w[i] : gd1;
        }

        // trailing update + norm downdate (row j freezes now)
#pragma unroll
        for (int k = j + 1; k < QC; ++k) {
#pragma unroll
            for (int s = 0; s < 4; ++s) x[s][k] = fmaf(-x[s][j], w[k], x[s][k]);
            const float rv = __shfl(x[0][k], j, 64);         // new row-j value of col k
            nrm2[k] = fmaf(-rv, rv, nrm2[k]);
        }
    }

    // ---- Z = U*T in place: z_j = u_j - sum_{i<j} z_i * g_ij  (no ds ops) ----
#pragma unroll
    for (int j = 1; j < QC; ++j) {
#pragma unroll
        for (int i = 0; i < j; ++i) {
            const int p = j*(j-1)/2 + i;
            const float g = (p < 64) ? __shfl(gd0, p, 64) : __shfl(gd1, p - 64, 64);
#pragma unroll
            for (int s = 0; s < 4; ++s) x[s][j] = fmaf(-x[s][i], g, x[s][j]);
        }
    }

    // ---- Q = E - Z*U1^T in place, right-to-left (col k needs only cols <= k) ----
#pragma unroll
    for (int k = QC - 1; k >= 0; --k) {
        float acc0 = (lane == k) ? 1.f : 0.f;  // diag of E (row k is slot 0, lane k)
        float acc1 = 0.f, acc2 = 0.f, acc3 = 0.f;
#pragma unroll
        for (int j = 0; j <= k; ++j) {
            const int q = k*(k+1)/2 + j;
            const float u1 = (q < 64)  ? __shfl(ud0, q, 64)
                           : (q < 128) ? __shfl(ud1, q - 64, 64)
                                       : __shfl(ud2, q - 128, 64);
            acc0 = fmaf(-x[0][j], u1, acc0);
            acc1 = fmaf(-x[1][j], u1, acc1);
            acc2 = fmaf(-x[2][j], u1, acc2);
            acc3 = fmaf(-x[3][j], u1, acc3);
        }
        x[0][k] = acc0; x[1][k] = acc1; x[2][k] = acc2; x[3][k] = acc3;
    }

    // ---- store ----
#pragma unroll
    for (int s = 0; s < 4; ++s) {
        const int rr = s * 64 + lane;
#pragma unroll
        for (int q4 = 0; q4 < 4; ++q4) {
            O4[rr * 4 + q4] = make_float4(x[s][q4*4+0], x[s][q4*4+1],
                                          x[s][q4*4+2], x[s][q4*4+3]);
        }
    }
}

extern "C" void kernel_launch(void* const* d_in, const int* in_sizes, int n_in,
                              void* d_out, int out_size, void* d_ws, size_t ws_size,
                              hipStream_t stream) {
    const float* X = (const float*)d_in[0];
    float*       O = (float*)d_out;
    qr_wy_kernel<<<BATCH / 4, 256, 0, stream>>>(X, O);
}

// Round 3
// 359.124 us; speedup vs baseline: 3.5785x; 3.5785x over previous
//
#include <hip/hip_runtime.h>

// Batched thin QR (Householder, LAPACK sign convention) for 8192 x (256x16) fp32.
// One 64-lane wave per matrix; lane l owns rows {l, l+64, l+128, l+192} in registers.
//
// Round-3: latency attack.
//  - All wave reductions via DPP v_add chains (VALU pipe) + readlane -> SGPR,
//    instead of 6 chained ds_swizzles (LDS pipe, ~250cy dependent latency).
//  - Column norms computed once, downdated by R_jt^2 -> ONE reduction batch per step.
//  - beta = 2/v'v analytic, dots use unscaled v -> sqrt/rcp off the critical path.
//  - Compact-WY Q formation: Gram (120 independent dots, one pipelined batch) -> LDS;
//    Z-recurrence and Q = E - Z*U1^T are pure FMAs + uniform LDS broadcasts.
//    (Round-2 lesson: uniform scalars in LDS, NOT lane-sliced VGPRs -> no spills.)

constexpr int BATCH = 8192;
constexpr int DROWS = 256;
constexpr int QC    = 16;

__device__ __forceinline__ float rdlane(float v, int l) {
    return __int_as_float(__builtin_amdgcn_readlane(__float_as_int(v), l));
}

template <int CTRL>
__device__ __forceinline__ float dpp_add(float x) {
    int y = __builtin_amdgcn_update_dpp(0, __float_as_int(x), CTRL, 0xf, 0xf, true);
    return x + __int_as_float(y);
}

// Full 64-lane sum, returned as a wave-uniform value (via lane 63 readlane -> SGPR).
__device__ __forceinline__ float wave_sum(float x) {
    x = dpp_add<0xB1>(x);   // quad_perm [1,0,3,2]  : xor 1
    x = dpp_add<0x4E>(x);   // quad_perm [2,3,0,1]  : xor 2
    x = dpp_add<0x141>(x);  // row_half_mirror      : 8-group sum
    x = dpp_add<0x140>(x);  // row_mirror           : 16-row sum
    x = dpp_add<0x142>(x);  // row_bcast15          : accumulate across rows
    x = dpp_add<0x143>(x);  // row_bcast31          : lanes 48-63 = full sum
    return rdlane(x, 63);
}

__global__ __launch_bounds__(256) void qr_wy_dpp_kernel(
    const float* __restrict__ in, float* __restrict__ out)
{
    const int lane = threadIdx.x & 63;
    const int wid  = threadIdx.x >> 6;
    const int b    = blockIdx.x * 4 + wid;

    __shared__ float gsh[4][QC * 17];   // Gram g_ij at [j*17+i], i<j
    __shared__ float ush[4][QC * 17];   // U1[k][j] = u_j[row k] at [k*17+j], j<=k
    float* __restrict__ gs = gsh[wid];
    float* __restrict__ us = ush[wid];

    const float4* __restrict__ A4 = (const float4*)(in  + (size_t)b * (DROWS * QC));
    float4*       __restrict__ O4 = (float4*)      (out + (size_t)b * (DROWS * QC));

    float x[4][QC];   // columns; become u_j, then z_j, then Q

    // ---- load ----
#pragma unroll
    for (int s = 0; s < 4; ++s) {
        const int rr = s * 64 + lane;
#pragma unroll
        for (int q4 = 0; q4 < 4; ++q4) {
            float4 t = A4[rr * 4 + q4];
            x[s][q4*4+0] = t.x; x[s][q4*4+1] = t.y;
            x[s][q4*4+2] = t.z; x[s][q4*4+3] = t.w;
        }
    }

    // ---- upfront column norms^2 (16 independent pipelined reductions) ----
    float nrm2[QC];
#pragma unroll
    for (int k = 0; k < QC; ++k) {
        float p = x[0][k]*x[0][k] + x[1][k]*x[1][k] + x[2][k]*x[2][k] + x[3][k]*x[3][k];
        nrm2[k] = wave_sum(p);   // reflectors preserve norms; downdated as rows freeze
    }

    // ---- Householder factorization ----
#pragma unroll
    for (int j = 0; j < QC; ++j) {
        const float xjj   = rdlane(x[0][j], j);              // pivot (row j)
        const float nrm   = sqrtf(nrm2[j]);
        const float alpha = -copysignf(nrm, xjj);            // LAPACK dlarfg sign
        const float vtv   = 2.f * (nrm2[j] - alpha * xjj);   // ||v||^2 (no cancellation)
        const float beta  = 2.f / vtv;                       // H = I - beta v v'
        const float sc    = sqrtf(beta);                     // u = v*sc (for WY phases)

        // form v_j in place (rows < j zeroed; rows < 16 live only in slot 0)
        x[0][j] = (lane < j) ? 0.f : (lane == j ? (xjj - alpha) : x[0][j]);

        // dots with trailing columns (independent, pipeline through VALU),
        // rank-1 update, and norm downdate with the frozen R_jt
#pragma unroll
        for (int t = j + 1; t < QC; ++t) {
            float d = x[0][j]*x[0][t] + x[1][j]*x[1][t] + x[2][j]*x[2][t] + x[3][j]*x[3][t];
            const float wb = beta * wave_sum(d);
#pragma unroll
            for (int s = 0; s < 4; ++s) x[s][t] = fmaf(-wb, x[s][j], x[s][t]);
            const float rv = rdlane(x[0][t], j);             // R_jt (row j frozen now)
            nrm2[t] = fmaf(-rv, rv, nrm2[t]);
        }

        // finalize u_j = v_j * sc (off the inter-step critical path)
        x[0][j] *= sc; x[1][j] *= sc; x[2][j] *= sc; x[3][j] *= sc;

        // persist U1 entries (rows j..15 of u_j live in slot 0, lanes j..15)
        if (lane >= j && lane < QC) us[lane * 17 + j] = x[0][j];
    }

    // ---- Gram batch: g_ij = u_i . u_j, 120 independent reductions ----
#pragma unroll
    for (int j = 1; j < QC; ++j) {
#pragma unroll
        for (int i = 0; i < j; ++i) {
            float d = x[0][i]*x[0][j] + x[1][i]*x[1][j] + x[2][i]*x[2][j] + x[3][i]*x[3][j];
            d = wave_sum(d);
            if (lane == 0) gs[j * 17 + i] = d;
        }
    }

    // ---- Z = U*T in place: z_j = u_j - sum_{i<j} z_i g_ij (FMAs + LDS broadcasts) ----
#pragma unroll
    for (int j = 1; j < QC; ++j) {
#pragma unroll
        for (int i = 0; i < j; ++i) {
            const float gij = gs[j * 17 + i];
#pragma unroll
            for (int s = 0; s < 4; ++s) x[s][j] = fmaf(-x[s][i], gij, x[s][j]);
        }
    }

    // ---- Q = E - Z*U1^T in place, right-to-left (col k uses cols <= k) ----
#pragma unroll
    for (int k = QC - 1; k >= 0; --k) {
        float a0 = (lane == k) ? 1.f : 0.f;   // E diag (row k = slot 0, lane k)
        float a1 = 0.f, a2 = 0.f, a3 = 0.f;
#pragma unroll
        for (int j = 0; j <= k; ++j) {
            const float u1 = us[k * 17 + j];
            a0 = fmaf(-x[0][j], u1, a0);
            a1 = fmaf(-x[1][j], u1, a1);
            a2 = fmaf(-x[2][j], u1, a2);
            a3 = fmaf(-x[3][j], u1, a3);
        }
        x[0][k] = a0; x[1][k] = a1; x[2][k] = a2; x[3][k] = a3;
    }

    // ---- store ----
#pragma unroll
    for (int s = 0; s < 4; ++s) {
        const int rr = s * 64 + lane;
#pragma unroll
        for (int q4 = 0; q4 < 4; ++q4) {
            O4[rr * 4 + q4] = make_float4(x[s][q4*4+0], x[s][q4*4+1],
                                          x[s][q4*4+2], x[s][q4*4+3]);
        }
    }
}

extern "C" void kernel_launch(void* const* d_in, const int* in_sizes, int n_in,
                              void* d_out, int out_size, void* d_ws, size_t ws_size,
                              hipStream_t stream) {
    const float* X = (const float*)d_in[0];
    float*       O = (float*)d_out;
    qr_wy_dpp_kernel<<<BATCH / 4, 256, 0, stream>>>(X, O);
}